// Round 3
// baseline (12352.214 us; speedup 1.0000x reference)
//
#include <hip/hip_runtime.h>
#include <cstdint>
#include <cstring>
#include <vector>
#include <algorithm>

// ---------------------------------------------------------------------------
// GRASPLayer round 3: fp32 pipeline (fp32 proved bit-equivalent to fp64 here),
// with the kmeans-init fix: JAX partitionable threefry 32-bit random_bits are
// bits1 ^ bits2 (XOR of both output words), not the first word alone.
// ---------------------------------------------------------------------------

namespace {
constexpr int Nn = 2048;
constexpr int Tt = 128;
constexpr int Dd = 256;
constexpr int Hh = 256;
constexpr int Kk = 12;
constexpr int MAXIT = 100;

constexpr int BN = 64;   // rows per block (GRU step)
constexpr int BC = 32;   // h-cols per block
constexpr int KC = 32;   // K-chunk
}

#define JAX_PARTITIONABLE 1   // 1: modern JAX default; 0: legacy threefry path

struct IdxArgs { int v[Kk]; };

__device__ __forceinline__ float sigm(float x) { return 1.0f / (1.0f + expf(-x)); }

// ---------------------------------------------------------------------------
__global__ void zerok(float* p, int n) {
  int i = blockIdx.x * blockDim.x + threadIdx.x;
  if (i < n) p[i] = 0.f;
}

// One GRU time step: rows with t>=len skip stores (state never consumed again).
// hfin captured at t==len-1.
__global__ __launch_bounds__(256) void gru_step(
    const float* __restrict__ x, const int* __restrict__ len,
    const float* __restrict__ Wih, const float* __restrict__ Whh,
    const float* __restrict__ bih, const float* __restrict__ bhh,
    const float* __restrict__ hprev, float* __restrict__ hcur,
    float* __restrict__ hfin, int t)
{
  __shared__ alignas(16) float xs[KC][BN + 4];       // [k][row]
  __shared__ alignas(16) float ws[3][KC][BC + 2];    // [gate][k][col]
  const int tid = threadIdx.x;
  const int tx = tid & 15;          // 16 col-groups of 2
  const int ty = tid >> 4;          // 16 row-groups of 4
  const int n0 = blockIdx.x * BN;
  const int c0 = blockIdx.y * BC;

  float aR[4][2] = {}; float aZ[4][2] = {}; float aXN[4][2] = {}; float aHN[4][2] = {};

  const int kk = tid & (KC - 1);
  const int rb = tid >> 5;

  // ---- input part: gx = x_t @ W_ih^T (K over D) ----
  for (int k0 = 0; k0 < Dd; k0 += KC) {
    #pragma unroll
    for (int i = 0; i < BN / 8; ++i) {
      int r = rb * 8 + i;
      xs[kk][r] = x[(size_t)(n0 + r) * (Tt * Dd) + (size_t)t * Dd + (k0 + kk)];
    }
    for (int idx = tid; idx < 3 * KC * BC; idx += 256) {
      int k = idx & (KC - 1);
      int c = (idx >> 5) & (BC - 1);
      int g = idx >> 10;
      ws[g][k][c] = Wih[(size_t)(g * Hh + c0 + c) * Dd + (k0 + k)];
    }
    __syncthreads();
    #pragma unroll 8
    for (int k = 0; k < KC; ++k) {
      float4 xv = *(const float4*)&xs[k][4 * ty];
      float2 wr = *(const float2*)&ws[0][k][2 * tx];
      float2 wz = *(const float2*)&ws[1][k][2 * tx];
      float2 wn = *(const float2*)&ws[2][k][2 * tx];
      const float xa[4] = {xv.x, xv.y, xv.z, xv.w};
      #pragma unroll
      for (int r = 0; r < 4; ++r) {
        aR[r][0]  += xa[r] * wr.x;  aR[r][1]  += xa[r] * wr.y;
        aZ[r][0]  += xa[r] * wz.x;  aZ[r][1]  += xa[r] * wz.y;
        aXN[r][0] += xa[r] * wn.x;  aXN[r][1] += xa[r] * wn.y;
      }
    }
    __syncthreads();
  }

  // ---- hidden part: gh = h_prev @ W_hh^T (K over H) ----
  for (int k0 = 0; k0 < Hh; k0 += KC) {
    #pragma unroll
    for (int i = 0; i < BN / 8; ++i) {
      int r = rb * 8 + i;
      xs[kk][r] = hprev[(size_t)(n0 + r) * Hh + (k0 + kk)];
    }
    for (int idx = tid; idx < 3 * KC * BC; idx += 256) {
      int k = idx & (KC - 1);
      int c = (idx >> 5) & (BC - 1);
      int g = idx >> 10;
      ws[g][k][c] = Whh[(size_t)(g * Hh + c0 + c) * Hh + (k0 + k)];
    }
    __syncthreads();
    #pragma unroll 8
    for (int k = 0; k < KC; ++k) {
      float4 xv = *(const float4*)&xs[k][4 * ty];
      float2 wr = *(const float2*)&ws[0][k][2 * tx];
      float2 wz = *(const float2*)&ws[1][k][2 * tx];
      float2 wn = *(const float2*)&ws[2][k][2 * tx];
      const float xa[4] = {xv.x, xv.y, xv.z, xv.w};
      #pragma unroll
      for (int r = 0; r < 4; ++r) {
        aR[r][0]  += xa[r] * wr.x;  aR[r][1]  += xa[r] * wr.y;
        aZ[r][0]  += xa[r] * wz.x;  aZ[r][1]  += xa[r] * wz.y;
        aHN[r][0] += xa[r] * wn.x;  aHN[r][1] += xa[r] * wn.y;
      }
    }
    __syncthreads();
  }

  // gate order r,z,n (PyTorch layout)
  #pragma unroll
  for (int r = 0; r < 4; ++r) {
    int n = n0 + 4 * ty + r;
    int L = len[n];
    if (t >= L) continue;
    #pragma unroll
    for (int c = 0; c < 2; ++c) {
      int C = c0 + 2 * tx + c;
      float rg = sigm(aR[r][c] + bih[C] + bhh[C]);
      float zg = sigm(aZ[r][c] + bih[Hh + C] + bhh[Hh + C]);
      float ng = tanhf(aXN[r][c] + bih[2 * Hh + C] + rg * (aHN[r][c] + bhh[2 * Hh + C]));
      float hp = hprev[(size_t)n * Hh + C];
      float hv = (1.f - zg) * ng + zg * hp;
      hcur[(size_t)n * Hh + C] = hv;
      if (t == L - 1) hfin[(size_t)n * Hh + C] = hv;
    }
  }
}

// ---------------------------------------------------------------------------
__global__ void km_init(const float* __restrict__ dat, float* __restrict__ cent, IdxArgs ia)
{
  int c = threadIdx.x;
  #pragma unroll
  for (int k = 0; k < Kk; ++k)
    cent[k * Hh + c] = dat[(size_t)ia.v[k] * Hh + c];
}

// Assign + per-block partial sums. Deterministic: per-wave LDS partials in
// fixed row order, combined in fixed wave order. No atomics.
__global__ __launch_bounds__(256) void km_assign(
    const float* __restrict__ dat, const float* __restrict__ cent,
    float* __restrict__ part, int* __restrict__ pcnt)
{
  __shared__ alignas(16) float cs[Kk][Hh];        // centers
  __shared__ alignas(16) float ps[4][Kk][Hh];     // per-wave partial sums
  __shared__ float c2s[Kk];
  __shared__ int pc[4][Kk];
  const int tid = threadIdx.x;
  const int lane = tid & 63;
  const int w = tid >> 6;

  for (int i = tid; i < Kk * Hh; i += 256) ((float*)cs)[i] = cent[i];
  for (int i = tid; i < 4 * Kk * Hh; i += 256) ((float*)ps)[i] = 0.f;
  if (tid < 4 * Kk) ((int*)pc)[tid] = 0;
  __syncthreads();
  if (tid < Kk) {
    float s = 0.f;
    for (int c = 0; c < Hh; ++c) { float v = cs[tid][c]; s += v * v; }
    c2s[tid] = s;
  }
  __syncthreads();

  const int base = blockIdx.x * 64 + w * 16;      // 16 rows per wave
  for (int rr = 0; rr < 16; ++rr) {
    const int n = base + rr;
    float4 v = *(const float4*)&dat[(size_t)n * Hh + lane * 4];
    float best = 3.4e38f; int bi = 0;
    #pragma unroll
    for (int k = 0; k < Kk; ++k) {
      float4 cv = *(const float4*)&cs[k][lane * 4];
      float p = v.x * cv.x + v.y * cv.y + v.z * cv.z + v.w * cv.w;
      #pragma unroll
      for (int m = 1; m < 64; m <<= 1) p += __shfl_xor(p, m, 64);
      float d = c2s[k] - 2.f * p;                 // x^2 constant per row
      if (d < best) { best = d; bi = k; }         // strict <: first-min = argmin
    }
    float4* dst = (float4*)&ps[w][bi][lane * 4];
    float4 cur = *dst;
    cur.x += v.x; cur.y += v.y; cur.z += v.z; cur.w += v.w;
    *dst = cur;
    if (lane == 0) pc[w][bi] += 1;
  }
  __syncthreads();
  const float* p0 = &ps[0][0][0];
  for (int i = tid; i < Kk * Hh; i += 256)
    part[(size_t)blockIdx.x * (Kk * Hh) + i] =
        p0[i] + p0[Kk * Hh + i] + p0[2 * Kk * Hh + i] + p0[3 * Kk * Hh + i];
  if (tid < Kk)
    pcnt[blockIdx.x * Kk + tid] = pc[0][tid] + pc[1][tid] + pc[2][tid] + pc[3][tid];
}

// Reduce 32 block-partials in fixed order; empty clusters keep old center.
__global__ __launch_bounds__(256) void km_update(
    const float* __restrict__ part, const int* __restrict__ pcnt,
    float* __restrict__ cent)
{
  int k = blockIdx.x, c = threadIdx.x;
  int cnt = 0;
  for (int p = 0; p < 32; ++p) cnt += pcnt[p * Kk + k];
  float s = 0.f;
  for (int p = 0; p < 32; ++p) s += part[(size_t)p * (Kk * Hh) + k * Hh + c];
  if (cnt > 0) cent[k * Hh + c] = s / (float)cnt;
}

// ---------------------------------------------------------------------------
// h1 = relu(centers@g1_w + g1_b); h2 = relu(h1@g2_w + g2_b). One block.
__global__ __launch_bounds__(256) void gcn(
    const float* __restrict__ cent, const float* __restrict__ g1w,
    const float* __restrict__ g1b, const float* __restrict__ g2w,
    const float* __restrict__ g2b, float* __restrict__ h2out)
{
  __shared__ float a[Kk][Hh];
  __shared__ float b[Kk][Hh];
  int c = threadIdx.x;
  for (int i = c; i < Kk * Hh; i += 256) ((float*)a)[i] = cent[i];
  __syncthreads();
  float acc[Kk];
  #pragma unroll
  for (int k = 0; k < Kk; ++k) acc[k] = 0.f;
  for (int j = 0; j < Hh; ++j) {
    float wv = g1w[(size_t)j * Hh + c];
    #pragma unroll
    for (int k = 0; k < Kk; ++k) acc[k] += a[k][j] * wv;
  }
  #pragma unroll
  for (int k = 0; k < Kk; ++k) b[k][c] = fmaxf(acc[k] + g1b[c], 0.f);
  __syncthreads();
  #pragma unroll
  for (int k = 0; k < Kk; ++k) acc[k] = 0.f;
  for (int j = 0; j < Hh; ++j) {
    float wv = g2w[(size_t)j * Hh + c];
    #pragma unroll
    for (int k = 0; k < Kk; ++k) acc[k] += b[k][j] * wv;
  }
  #pragma unroll
  for (int k = 0; k < Kk; ++k) h2out[k * Hh + c] = fmaxf(acc[k] + g2b[c], 0.f);
}

// scores = softmax(relu(ht@centers^T)); clu = scores@h2; gated blend. 1 block/row.
__global__ __launch_bounds__(256) void finalk(
    const float* __restrict__ hfin, const float* __restrict__ cent,
    const float* __restrict__ h2, const float* __restrict__ w1w,
    const float* __restrict__ w1b, const float* __restrict__ w2w,
    const float* __restrict__ w2b, float* __restrict__ out)
{
  __shared__ alignas(16) float cs[Kk][Hh];
  __shared__ alignas(16) float hs[Kk][Hh];
  __shared__ float red[4];
  const int tid = threadIdx.x, lane = tid & 63, w = tid >> 6;
  const int n = blockIdx.x;
  for (int i = tid; i < Kk * Hh; i += 256) { ((float*)cs)[i] = cent[i]; ((float*)hs)[i] = h2[i]; }
  float ht = hfin[(size_t)n * Hh + tid];
  __syncthreads();

  auto bred = [&](float v) -> float {
    #pragma unroll
    for (int m = 1; m < 64; m <<= 1) v += __shfl_xor(v, m, 64);
    __syncthreads();
    if (lane == 0) red[w] = v;
    __syncthreads();
    return red[0] + red[1] + red[2] + red[3];
  };

  float ev[Kk];
  #pragma unroll
  for (int k = 0; k < Kk; ++k)
    ev[k] = fmaxf(bred(ht * cs[k][tid]), 0.f);

  float mx = ev[0];
  #pragma unroll
  for (int k = 1; k < Kk; ++k) mx = fmaxf(mx, ev[k]);
  float se = 0.f; float sc[Kk];
  #pragma unroll
  for (int k = 0; k < Kk; ++k) { sc[k] = expf(ev[k] - mx); se += sc[k]; }
  float inv = 1.f / se;
  float clu = 0.f;
  #pragma unroll
  for (int k = 0; k < Kk; ++k) clu += sc[k] * inv * hs[k][tid];

  float r1 = bred(clu * w1w[tid]);
  float r2 = bred(ht * w2w[tid]);
  float a1 = sigm(r1 + w1b[0]);
  float a2 = sigm(r2 + w2b[0]);
  float wn = a1 / (a1 + a2);
  out[(size_t)n * Hh + tid] = wn * clu + (1.f - wn) * ht;
}

// ---------------------------------------------------------------------------
// Host-side threefry2x32 (JAX), reproducing jax.random.permutation(key(42), 2048)[:12].
static void tf2x32(uint32_t k0, uint32_t k1, uint32_t c0, uint32_t c1,
                   uint32_t& o0, uint32_t& o1) {
  uint32_t ks2 = k0 ^ k1 ^ 0x1BD11BDAu;
  uint32_t x0 = c0 + k0, x1 = c1 + k1;
#define TFR(r) do { x0 += x1; x1 = (x1 << (r)) | (x1 >> (32 - (r))); x1 ^= x0; } while (0)
  TFR(13); TFR(15); TFR(26); TFR(6);
  x0 += k1;  x1 += ks2 + 1u;
  TFR(17); TFR(29); TFR(16); TFR(24);
  x0 += ks2; x1 += k0 + 2u;
  TFR(13); TFR(15); TFR(26); TFR(6);
  x0 += k0;  x1 += k1 + 3u;
  TFR(17); TFR(29); TFR(16); TFR(24);
  x0 += k1;  x1 += ks2 + 4u;
  TFR(13); TFR(15); TFR(26); TFR(6);
  x0 += ks2; x1 += k0 + 5u;
#undef TFR
  o0 = x0; o1 = x1;
}

static void compute_idx(int* out12) {
  uint32_t kh = 0u, kl = 42u;     // jax.random.key(42) -> (0, 42)
  std::vector<int> perm(Nn);
  for (int i = 0; i < Nn; ++i) perm[i] = i;
  std::vector<uint32_t> bits(Nn);
  std::vector<int> pos(Nn);
  // num_rounds = ceil(3*ln(2048)/ln(2^32-1)) = 2
  for (int round = 0; round < 2; ++round) {
    uint32_t nh, nl, sh, sl;
#if JAX_PARTITIONABLE
    // split: subkey_i = both output words of threefry(key, (0, i))
    tf2x32(kh, kl, 0u, 0u, nh, nl);
    tf2x32(kh, kl, 0u, 1u, sh, sl);
#else
    { uint32_t a0, a1, b0, b1;
      tf2x32(kh, kl, 0u, 2u, a0, b0);
      tf2x32(kh, kl, 1u, 3u, a1, b1);
      nh = a0; nl = a1; sh = b0; sl = b1; }
#endif
    kh = nh; kl = nl;
#if JAX_PARTITIONABLE
    // partitionable random_bits(32): bits[i] = o0 ^ o1 at counter (0, i)
    for (uint32_t i = 0; i < (uint32_t)Nn; ++i) {
      uint32_t o0, o1; tf2x32(sh, sl, 0u, i, o0, o1); bits[i] = o0 ^ o1;
    }
#else
    // legacy random_bits(32): counters [0..n) split-paired (i, n/2+i)
    for (uint32_t i = 0; i < (uint32_t)Nn / 2; ++i) {
      uint32_t o0, o1; tf2x32(sh, sl, i, (uint32_t)(Nn / 2) + i, o0, o1);
      bits[i] = o0; bits[Nn / 2 + i] = o1;
    }
#endif
    for (int i = 0; i < Nn; ++i) pos[i] = i;
    std::stable_sort(pos.begin(), pos.end(),
                     [&](int a, int b) { return bits[a] < bits[b]; });
    std::vector<int> np(Nn);
    for (int i = 0; i < Nn; ++i) np[i] = perm[pos[i]];
    perm.swap(np);
  }
  for (int k = 0; k < Kk; ++k) out12[k] = perm[k];
}

// ---------------------------------------------------------------------------
extern "C" void kernel_launch(void* const* d_in, const int* in_sizes, int n_in,
                              void* d_out, int out_size, void* d_ws, size_t ws_size,
                              hipStream_t stream) {
  const float* x   = (const float*)d_in[0];
  const int*   len = (const int*)d_in[1];
  const float* Wih = (const float*)d_in[2];
  const float* Whh = (const float*)d_in[3];
  const float* bih = (const float*)d_in[4];
  const float* bhh = (const float*)d_in[5];
  const float* w1w = (const float*)d_in[6];
  const float* w1b = (const float*)d_in[7];
  const float* w2w = (const float*)d_in[8];
  const float* w2b = (const float*)d_in[9];
  const float* g1w = (const float*)d_in[10];
  const float* g1b = (const float*)d_in[11];
  const float* g2w = (const float*)d_in[12];
  const float* g2b = (const float*)d_in[13];
  float* out = (float*)d_out;

  float* wsf  = (float*)d_ws;
  float* hA   = wsf;                        // N*H
  float* hB   = hA + (size_t)Nn * Hh;       // N*H
  float* hfin = hB + (size_t)Nn * Hh;       // N*H
  float* cent = hfin + (size_t)Nn * Hh;     // K*H
  float* h2g  = cent + Kk * Hh;             // K*H
  float* part = h2g + Kk * Hh;              // 32*K*H
  int*   pcnt = (int*)(part + 32 * Kk * Hh);// 32*K

  IdxArgs ia;
  compute_idx(ia.v);                        // host, deterministic, capture-safe

  zerok<<<(Nn * Hh + 255) / 256, 256, 0, stream>>>(hA, Nn * Hh);

  dim3 gg(Nn / BN, Hh / BC);
  for (int t = 0; t < Tt; ++t) {
    const float* hp = (t & 1) ? hB : hA;
    float* hc = (t & 1) ? hA : hB;
    gru_step<<<gg, 256, 0, stream>>>(x, len, Wih, Whh, bih, bhh, hp, hc, hfin, t);
  }

  km_init<<<1, 256, 0, stream>>>(hfin, cent, ia);
  for (int it = 0; it < MAXIT; ++it) {
    km_assign<<<32, 256, 0, stream>>>(hfin, cent, part, pcnt);
    km_update<<<Kk, 256, 0, stream>>>(part, pcnt, cent);
  }

  gcn<<<1, 256, 0, stream>>>(cent, g1w, g1b, g2w, g2b, h2g);
  finalk<<<Nn, 256, 0, stream>>>(hfin, cent, h2g, w1w, w1b, w2w, w2b, out);
}